// Round 2
// baseline (500.298 us; speedup 1.0000x reference)
//
#include <hip/hip_runtime.h>
#include <hip/hip_bf16.h>
#include <cstdint>

// MCRNNVAE eval forward, algebraically collapsed:
//   h_{t+1} = tanh(x_t@R_c + r0_c + h_t@Q_c)
//   mu_t    = x_t@N_c + h_t@M2_c + n0_c
// R,Q,N,M2,r0,n0 precomputed from the raw weights (exact linear algebra).
// Round 6: full revert to the proven round-0 structure (kernU2 + kernB2 + kernC3).
// Single change: kernB3 = kernB2 with the two per-step __syncthreads() replaced by
// {s_waitcnt lgkmcnt(0); s_barrier; sched_barrier(0)}. hipcc lowers __syncthreads
// to s_waitcnt vmcnt(0) lgkmcnt(0) + s_barrier, which drags the ~500-900-cycle
// global U-load/Hs-store latency into the serial critical path TWICE per step.
// The raw barrier keeps global ops in flight across barriers; vmcnt waits occur
// only at register use (one full step after issue — fully hidden).

typedef __attribute__((ext_vector_type(8))) short short8;
typedef __attribute__((ext_vector_type(4))) float float4v;

__device__ __forceinline__ float bf2f(unsigned short u){
  union { unsigned int i; float f; } v; v.i = ((unsigned int)u) << 16; return v.f;
}
__device__ __forceinline__ unsigned short f2bf(float f){
  union { float f; unsigned int i; } v; v.f = f;
  unsigned int r = v.i + 0x7fffu + ((v.i >> 16) & 1u);
  return (unsigned short)(r >> 16);
}
__device__ __forceinline__ void st_bf2(unsigned short* p, float a, float b){
  unsigned int pa = f2bf(a), pb = f2bf(b);
  *(unsigned int*)p = pa | (pb << 16);
}
__device__ __forceinline__ float ftanh(float x){
  x = fminf(15.f, fmaxf(-15.f, x));
  float e = __expf(2.f * x);
  return (e - 1.f) * __builtin_amdgcn_rcpf(e + 1.f);
}
// LDS-only barrier: order LDS ops, leave global loads/stores in flight.
__device__ __forceinline__ void ldsbar(){
  asm volatile("s_waitcnt lgkmcnt(0)" ::: "memory");
  __builtin_amdgcn_s_barrier();
  __builtin_amdgcn_sched_barrier(0);
}

__device__ __forceinline__ float dotSB(const float* __restrict__ a,
                                       const float* __restrict__ b, int K, int ldb){
  float s = 0.f;
  #pragma unroll 4
  for (int k = 0; k < K; ++k) s = fmaf(a[k], b[(size_t)k * ldb], s);
  return s;
}

// ---- precompute stage 1: T1 = We1@Wqm, T2 = We2@Wqm, c0a = be@Wqm + bqm
__global__ void pre1(const float* __restrict__ encW, const float* __restrict__ encb,
                     const float* __restrict__ Wqm, const float* __restrict__ bqm,
                     float* __restrict__ T1, float* __restrict__ T2, float* __restrict__ c0a){
  int i = blockIdx.x * 256 + threadIdx.x;
  if (i < 24576){
    int c = i >> 13, rr = (i >> 6) & 127, l = i & 63;
    T1[i] = dotSB(encW + ((size_t)c*384 + rr)*128, Wqm + (size_t)c*8192 + l, 128, 64);
  } else if (i < 73728){
    int j = i - 24576; int c = j >> 14, rr = (j >> 6) & 255, l = j & 63;
    T2[j] = dotSB(encW + ((size_t)c*384 + 128 + rr)*128, Wqm + (size_t)c*8192 + l, 128, 64);
  } else if (i < 73920){
    int j = i - 73728; int c = j >> 6, l = j & 63;
    c0a[j] = dotSB(encb + c*128, Wqm + (size_t)c*8192 + l, 128, 64) + bqm[j];
  }
}

// ---- stage 2: A = T1@Wz, Bm = T2@Wz, c0 = c0a@Wz + bz
__global__ void pre2(const float* __restrict__ T1, const float* __restrict__ T2,
                     const float* __restrict__ c0a, const float* __restrict__ Wz,
                     const float* __restrict__ bz,
                     float* __restrict__ A, float* __restrict__ Bm, float* __restrict__ c0){
  int i = blockIdx.x * 256 + threadIdx.x;
  if (i < 49152){
    int c = i >> 14, rr = (i >> 7) & 127, n = i & 127;
    A[i] = dotSB(T1 + ((size_t)c*128 + rr)*64, Wz + n, 64, 128);
  } else if (i < 147456){
    int j = i - 49152; int c = j >> 15, rr = (j >> 7) & 255, n = j & 127;
    Bm[j] = dotSB(T2 + ((size_t)c*256 + rr)*64, Wz + n, 64, 128);
  } else if (i < 147840){
    int j = i - 147456; int c = j >> 7, n = j & 127;
    c0[j] = dotSB(c0a + c*64, Wz + n, 64, 128) + bz[n];
  }
}

// ---- stage 3: P = Wi1 + A@Wi2; Q = Whh + Bm@Wi2; r = c0@Wi2 + bih + bhh;
//               D1 = A@Wd1; E1 = Wd2 + Bm@Wd1; m0a = c0@Wd1 + bd
__global__ void pre3(const float* __restrict__ A, const float* __restrict__ Bm,
                     const float* __restrict__ c0, const float* __restrict__ Wih,
                     const float* __restrict__ Whh, const float* __restrict__ bih,
                     const float* __restrict__ bhh, const float* __restrict__ decW,
                     const float* __restrict__ decb,
                     float* __restrict__ P, float* __restrict__ Q, float* __restrict__ r,
                     float* __restrict__ D1, float* __restrict__ E1, float* __restrict__ m0a){
  int i = blockIdx.x * 256 + threadIdx.x;
  const float* Wi2 = Wih + 128*256;
  if (i < 98304){
    int c = i >> 15, rr = (i >> 8) & 127, n = i & 255;
    P[i] = Wih[rr*256 + n] + dotSB(A + ((size_t)c*128 + rr)*128, Wi2 + n, 128, 256);
  } else if (i < 294912){
    int j = i - 98304; int c = j >> 16, rr = (j >> 8) & 255, n = j & 255;
    Q[j] = Whh[rr*256 + n] + dotSB(Bm + ((size_t)c*256 + rr)*128, Wi2 + n, 128, 256);
  } else if (i < 295680){
    int j = i - 294912; int c = j >> 8, n = j & 255;
    r[j] = dotSB(c0 + c*128, Wi2 + n, 128, 256) + bih[n] + bhh[n];
  } else if (i < 344832){
    int j = i - 295680; int c = j >> 14, rr = (j >> 7) & 127, n = j & 127;
    D1[j] = dotSB(A + ((size_t)c*128 + rr)*128, decW + (size_t)c*49152 + n, 128, 128);
  } else if (i < 443136){
    int j = i - 344832; int c = j >> 15, rr = (j >> 7) & 255, n = j & 127;
    E1[j] = decW[(size_t)c*49152 + (size_t)(128 + rr)*128 + n]
          + dotSB(Bm + ((size_t)c*256 + rr)*128, decW + (size_t)c*49152 + n, 128, 128);
  } else if (i < 443520){
    int j = i - 443136; int c = j >> 7, n = j & 127;
    m0a[j] = dotSB(c0 + c*128, decW + (size_t)c*49152 + n, 128, 128) + decb[j];
  }
}

// ---- stage 4: R = Wx@P; r0 = bx@P + r; M1 = D1@Wpm; M2 = E1@Wpm; m0 = m0a@Wpm + bpm
__global__ void pre4(const float* __restrict__ Wx, const float* __restrict__ bx,
                     const float* __restrict__ P, const float* __restrict__ r,
                     const float* __restrict__ D1, const float* __restrict__ E1,
                     const float* __restrict__ m0a, const float* __restrict__ Wpm,
                     const float* __restrict__ bpm,
                     float* __restrict__ R, float* __restrict__ r0,
                     float* __restrict__ M1, float* __restrict__ M2, float* __restrict__ m0){
  int i = blockIdx.x * 256 + threadIdx.x;
  if (i < 98304){
    int c = i >> 15, rr = (i >> 8) & 127, n = i & 255;
    R[i] = dotSB(Wx + ((size_t)c*128 + rr)*128, P + (size_t)c*32768 + n, 128, 256);
  } else if (i < 99072){
    int j = i - 98304; int c = j >> 8, n = j & 255;
    r0[j] = dotSB(bx + c*128, P + (size_t)c*32768 + n, 128, 256) + r[j];
  } else if (i < 148224){
    int j = i - 99072; int c = j >> 14, rr = (j >> 7) & 127, n = j & 127;
    M1[j] = dotSB(D1 + ((size_t)c*128 + rr)*128, Wpm + (size_t)c*16384 + n, 128, 128);
  } else if (i < 246528){
    int j = i - 148224; int c = j >> 15, rr = (j >> 7) & 255, n = j & 127;
    M2[j] = dotSB(E1 + ((size_t)c*256 + rr)*128, Wpm + (size_t)c*16384 + n, 128, 128);
  } else if (i < 246912){
    int j = i - 246528; int c = j >> 7, n = j & 127;
    m0[j] = dotSB(m0a + c*128, Wpm + (size_t)c*16384 + n, 128, 128) + bpm[j];
  }
}

// ---- stage 5: Nn = Wx@M1; n0 = bx@M1 + m0
__global__ void pre5(const float* __restrict__ Wx, const float* __restrict__ bx,
                     const float* __restrict__ M1, const float* __restrict__ m0,
                     float* __restrict__ Nn, float* __restrict__ n0){
  int i = blockIdx.x * 256 + threadIdx.x;
  if (i < 49152){
    int c = i >> 14, rr = (i >> 7) & 127, n = i & 127;
    Nn[i] = dotSB(Wx + ((size_t)c*128 + rr)*128, M1 + (size_t)c*16384 + n, 128, 128);
  } else if (i < 49536){
    int j = i - 49152; int c = j >> 7, n = j & 127;
    n0[j] = dotSB(bx + c*128, M1 + (size_t)c*16384 + n, 128, 128) + m0[j];
  }
}

#define MFMA_BF16 __builtin_amdgcn_mfma_f32_16x16x32_bf16

// ---- kernU2: U = x@R + r0 (bf16 out) via MFMA. 1200 blocks x 512 thr (8 waves).
// Wave w owns cols [32w,32w+32); 8 m-tiles of 16 rows per block. x staged fp32->bf16
// in LDS (row stride 136: bank groups spread, 2-way max aliasing = free).
__global__ __launch_bounds__(512, 2)
void kernU2(const float* __restrict__ x, const float* __restrict__ Rg,
            const float* __restrict__ r0g, unsigned short* __restrict__ U){
  __shared__ unsigned short xs[128][136];
  const int m0 = blockIdx.x * 128;
  const int c  = m0 / 51200;                   // 400 blocks/channel, no straddle
  const int w  = threadIdx.x >> 6;
  const int l  = threadIdx.x & 63;
  const int q  = l >> 4, m = l & 15;
  const float* __restrict__ Rc = Rg + (size_t)c * 32768;   // [128][256]

  // R B-frags (bf16): B[k=32kt+8q+j][n=32w+16nt+m]
  short8 rf[4][2];
  #pragma unroll
  for (int kt = 0; kt < 4; ++kt)
    #pragma unroll
    for (int nt = 0; nt < 2; ++nt){
      union { short8 v; unsigned short u[8]; } tmp;
      const int col = 32*w + 16*nt + m;
      #pragma unroll
      for (int j = 0; j < 8; ++j)
        tmp.u[j] = f2bf(Rc[(size_t)(32*kt + 8*q + j)*256 + col]);
      rf[kt][nt] = tmp.v;
    }
  const float r0v0 = r0g[c*256 + 32*w + m];
  const float r0v1 = r0g[c*256 + 32*w + 16 + m];

  // stage x block rows [m0,m0+128) cols [0,128) -> LDS bf16
  {
    const int r  = threadIdx.x >> 2;           // 0..127
    const int c0 = (threadIdx.x & 3) * 32;     // 0/32/64/96, coalesced float4 loads
    const float* xr = x + (size_t)(m0 + r)*128 + c0;
    #pragma unroll
    for (int i = 0; i < 8; ++i){
      float4 v = *(const float4*)(xr + 4*i);
      st_bf2(&xs[r][c0 + 4*i],     v.x, v.y);
      st_bf2(&xs[r][c0 + 4*i + 2], v.z, v.w);
    }
  }
  __syncthreads();

  #pragma unroll 1
  for (int mt = 0; mt < 8; ++mt){
    float4v a0 = { r0v0, r0v0, r0v0, r0v0 };
    float4v a1 = { r0v1, r0v1, r0v1, r0v1 };
    #pragma unroll
    for (int kt = 0; kt < 4; ++kt){
      short8 af = *(const short8*)&xs[16*mt + m][32*kt + 8*q];
      a0 = MFMA_BF16(af, rf[kt][0], a0, 0,0,0);
      a1 = MFMA_BF16(af, rf[kt][1], a1, 0,0,0);
    }
    unsigned short* ub = U + (size_t)(m0 + 16*mt + 4*q)*256;
    ub[0*256 + 32*w + m]      = f2bf(a0.x);
    ub[1*256 + 32*w + m]      = f2bf(a0.y);
    ub[2*256 + 32*w + m]      = f2bf(a0.z);
    ub[3*256 + 32*w + m]      = f2bf(a0.w);
    ub[0*256 + 32*w + 16 + m] = f2bf(a1.x);
    ub[1*256 + 32*w + 16 + m] = f2bf(a1.y);
    ub[2*256 + 32*w + 16 + m] = f2bf(a1.z);
    ub[3*256 + 32*w + 16 + m] = f2bf(a1.w);
  }
}

// ---- kernB3: recurrence h_{t+1} = tanh(U_t + h_t@Q_c) via MFMA.
// 96 blocks = 3 channels x 32 (16 batch rows each), 512 threads = 8 waves.
// Identical to proven kernB2 EXCEPT: per-step barriers are raw s_barrier with
// lgkmcnt(0)-only drain (no vmcnt(0)) so the U prefetch loads and Hs stores
// stay in flight across barriers instead of serializing ~2x900cy per step.
__global__ __launch_bounds__(512, 2)
void kernB3(const unsigned short* __restrict__ U, const float* __restrict__ Qg,
            const float* __restrict__ h0, unsigned short* __restrict__ Hs){
  __shared__ unsigned short hHi[16][264];
  __shared__ unsigned short hLo[16][264];
  const int c  = blockIdx.x >> 5;
  const int b0 = (blockIdx.x & 31) << 4;
  const int w  = threadIdx.x >> 6;
  const int l  = threadIdx.x & 63;
  const int q  = l >> 4, m = l & 15;
  const float* __restrict__ Qc = Qg + (size_t)c * 65536;

  short8 qf[8][2];
  #pragma unroll
  for (int kt = 0; kt < 8; ++kt)
    #pragma unroll
    for (int nt = 0; nt < 2; ++nt){
      union { short8 v; unsigned short u[8]; } tmp;
      const int col = 32*w + 16*nt + m;
      #pragma unroll
      for (int j = 0; j < 8; ++j)
        tmp.u[j] = f2bf(Qc[(size_t)(32*kt + 8*q + j)*256 + col]);
      qf[kt][nt] = tmp.v;
    }

  unsigned short hiR[8];
  #pragma unroll
  for (int nt = 0; nt < 2; ++nt){
    const int col = 32*w + 16*nt + m;
    #pragma unroll
    for (int r = 0; r < 4; ++r){
      const int row = 4*q + r;
      float v = h0[((size_t)c*512 + b0 + row)*256 + col];
      unsigned short hi = f2bf(v);
      hiR[nt*4 + r] = hi;
      hHi[row][col] = hi;
      hLo[row][col] = f2bf(v - bf2f(hi));
    }
  }
  __syncthreads();

  unsigned short un[8];
  #pragma unroll
  for (int nt = 0; nt < 2; ++nt)
    #pragma unroll
    for (int r = 0; r < 4; ++r)
      un[nt*4 + r] = U[((size_t)(c*100 + 0)*512 + b0 + 4*q + r)*256 + 32*w + 16*nt + m];

  #pragma unroll 1
  for (int t = 0; t < 100; ++t){
    const size_t rowbase = (size_t)(c*100 + t)*512 + b0;
    #pragma unroll
    for (int nt = 0; nt < 2; ++nt)
      #pragma unroll
      for (int r = 0; r < 4; ++r)
        Hs[(rowbase + 4*q + r)*256 + 32*w + 16*nt + m] = hiR[nt*4 + r];

    float4v acc0 = { bf2f(un[0]), bf2f(un[1]), bf2f(un[2]), bf2f(un[3]) };
    float4v acc1 = { bf2f(un[4]), bf2f(un[5]), bf2f(un[6]), bf2f(un[7]) };

    const int tn = (t < 99) ? t + 1 : 99;
    #pragma unroll
    for (int nt = 0; nt < 2; ++nt)
      #pragma unroll
      for (int r = 0; r < 4; ++r)
        un[nt*4 + r] = U[((size_t)(c*100 + tn)*512 + b0 + 4*q + r)*256 + 32*w + 16*nt + m];

    #pragma unroll
    for (int kt = 0; kt < 8; ++kt){
      short8 ahi = *(const short8*)&hHi[m][32*kt + 8*q];
      short8 alo = *(const short8*)&hLo[m][32*kt + 8*q];
      acc0 = MFMA_BF16(ahi, qf[kt][0], acc0, 0,0,0);
      acc1 = MFMA_BF16(ahi, qf[kt][1], acc1, 0,0,0);
      acc0 = MFMA_BF16(alo, qf[kt][0], acc0, 0,0,0);
      acc1 = MFMA_BF16(alo, qf[kt][1], acc1, 0,0,0);
    }

    float hn[8];
    hn[0] = ftanh(acc0.x); hn[1] = ftanh(acc0.y); hn[2] = ftanh(acc0.z); hn[3] = ftanh(acc0.w);
    hn[4] = ftanh(acc1.x); hn[5] = ftanh(acc1.y); hn[6] = ftanh(acc1.z); hn[7] = ftanh(acc1.w);

    ldsbar();   // reads of hHi/hLo complete (lgkm only; globals stay in flight)
    #pragma unroll
    for (int nt = 0; nt < 2; ++nt){
      const int col = 32*w + 16*nt + m;
      #pragma unroll
      for (int r = 0; r < 4; ++r){
        const int row = 4*q + r;
        float v = hn[nt*4 + r];
        unsigned short hi = f2bf(v);
        hiR[nt*4 + r] = hi;
        hHi[row][col] = hi;
        hLo[row][col] = f2bf(v - bf2f(hi));
      }
    }
    ldsbar();   // writes visible to all waves (lgkm only)
  }
}

// ---- kernC3: out = x@Nn + Hs@M2 + n0 via MFMA. 1200 blocks x 512 thr. (proven)
__global__ __launch_bounds__(512, 2)
void kernC3(const float* __restrict__ x, const unsigned short* __restrict__ Hs,
            const float* __restrict__ Nn, const float* __restrict__ M2,
            const float* __restrict__ n0, float* __restrict__ out){
  __shared__ unsigned short xs[128][136];
  const int m0 = blockIdx.x * 128;
  const int c  = m0 / 51200;
  const int w  = threadIdx.x >> 6;
  const int l  = threadIdx.x & 63;
  const int q  = l >> 4, m = l & 15;
  const int col = 16*w + m;
  const float* __restrict__ Nc  = Nn + (size_t)c * 16384;   // [128][128]
  const float* __restrict__ M2c = M2 + (size_t)c * 32768;   // [256][128]

  short8 bw[12];
  #pragma unroll
  for (int kt = 0; kt < 4; ++kt){
    union { short8 v; unsigned short u[8]; } tmp;
    #pragma unroll
    for (int j = 0; j < 8; ++j)
      tmp.u[j] = f2bf(Nc[(size_t)(32*kt + 8*q + j)*128 + col]);
    bw[kt] = tmp.v;
  }
  #pragma unroll
  for (int kt = 0; kt < 8; ++kt){
    union { short8 v; unsigned short u[8]; } tmp;
    #pragma unroll
    for (int j = 0; j < 8; ++j)
      tmp.u[j] = f2bf(M2c[(size_t)(32*kt + 8*q + j)*128 + col]);
    bw[4 + kt] = tmp.v;
  }
  const float nz = n0[c*128 + col];

  {
    const int r  = threadIdx.x >> 2;
    const int c0 = (threadIdx.x & 3) * 32;
    const float* xr = x + (size_t)(m0 + r)*128 + c0;
    #pragma unroll
    for (int i = 0; i < 8; ++i){
      float4 v = *(const float4*)(xr + 4*i);
      st_bf2(&xs[r][c0 + 4*i],     v.x, v.y);
      st_bf2(&xs[r][c0 + 4*i + 2], v.z, v.w);
    }
  }
  __syncthreads();

  #pragma unroll 1
  for (int mt = 0; mt < 8; ++mt){
    float4v aa = { nz, nz, nz, nz }, ab = { 0.f, 0.f, 0.f, 0.f };
    #pragma unroll
    for (int kt = 0; kt < 4; ++kt){
      short8 af = *(const short8*)&xs[16*mt + m][32*kt + 8*q];
      if (kt & 1) ab = MFMA_BF16(af, bw[kt], ab, 0,0,0);
      else        aa = MFMA_BF16(af, bw[kt], aa, 0,0,0);
    }
    const size_t mrow = (size_t)(m0 + 16*mt) + m;
    #pragma unroll
    for (int kt = 0; kt < 8; ++kt){
      short8 af = *(const short8*)&Hs[mrow*256 + 32*kt + 8*q];
      if (kt & 1) ab = MFMA_BF16(af, bw[4+kt], ab, 0,0,0);
      else        aa = MFMA_BF16(af, bw[4+kt], aa, 0,0,0);
    }
    float* ob = out + (size_t)(m0 + 16*mt + 4*q)*128 + col;
    ob[0]   = aa.x + ab.x;
    ob[128] = aa.y + ab.y;
    ob[256] = aa.z + ab.z;
    ob[384] = aa.w + ab.w;
  }
}

extern "C" void kernel_launch(void* const* d_in, const int* in_sizes, int n_in,
                              void* d_out, int out_size, void* d_ws, size_t ws_size,
                              hipStream_t stream){
  const float* x    = (const float*)d_in[0];
  const float* Wx   = (const float*)d_in[1];
  const float* bx   = (const float*)d_in[2];
  const float* encW = (const float*)d_in[3];
  const float* encb = (const float*)d_in[4];
  const float* Wqm  = (const float*)d_in[5];
  const float* bqm  = (const float*)d_in[6];
  const float* Wz   = (const float*)d_in[7];
  const float* bz   = (const float*)d_in[8];
  const float* decW = (const float*)d_in[9];
  const float* decb = (const float*)d_in[10];
  const float* Wpm  = (const float*)d_in[11];
  const float* bpm  = (const float*)d_in[12];
  const float* Wih  = (const float*)d_in[13];
  const float* Whh  = (const float*)d_in[14];
  const float* bih  = (const float*)d_in[15];
  const float* bhh  = (const float*)d_in[16];
  const float* h0   = (const float*)d_in[17];

  float* ws = (float*)d_ws;
  size_t off = 0;
  auto alloc = [&](size_t n){ float* p = ws + off; off += n; return p; };
  float* T1  = alloc(24576);  float* T2  = alloc(49152);  float* c0a = alloc(192);
  float* A   = alloc(49152);  float* Bm  = alloc(98304);  float* c0  = alloc(384);
  float* P   = alloc(98304);  float* Q   = alloc(196608); float* r   = alloc(768);
  float* D1  = alloc(49152);  float* E1  = alloc(98304);  float* m0a = alloc(384);
  float* R   = alloc(98304);  float* r0  = alloc(768);
  float* M1  = alloc(49152);  float* M2  = alloc(98304);  float* m0  = alloc(384);
  float* Nn  = alloc(49152);  float* n0  = alloc(384);
  // Hs: 39,321,600 bf16 elements = 19,660,800 float slots (full size).
  unsigned short* Hs = (unsigned short*)(ws + off); off += 19660800;
  // U (bf16, 39.3M elems = 78.64 MB) lives in d_out (exact fit); consumed by
  // kernB3 before kernC3 overwrites d_out with the final result.
  unsigned short* U  = (unsigned short*)d_out;

  hipLaunchKernelGGL(pre1, dim3(289),  dim3(256), 0, stream, encW, encb, Wqm, bqm, T1, T2, c0a);
  hipLaunchKernelGGL(pre2, dim3(578),  dim3(256), 0, stream, T1, T2, c0a, Wz, bz, A, Bm, c0);
  hipLaunchKernelGGL(pre3, dim3(1733), dim3(256), 0, stream, A, Bm, c0, Wih, Whh, bih, bhh,
                     decW, decb, P, Q, r, D1, E1, m0a);
  hipLaunchKernelGGL(pre4, dim3(965),  dim3(256), 0, stream, Wx, bx, P, r, D1, E1, m0a,
                     Wpm, bpm, R, r0, M1, M2, m0);
  hipLaunchKernelGGL(pre5, dim3(194),  dim3(256), 0, stream, Wx, bx, M1, m0, Nn, n0);
  hipLaunchKernelGGL(kernU2, dim3(1200), dim3(512), 0, stream, x, R, r0, U);
  hipLaunchKernelGGL(kernB3, dim3(96),   dim3(512), 0, stream, U, Q, h0, Hs);
  hipLaunchKernelGGL(kernC3, dim3(1200), dim3(512), 0, stream, x, Hs, Nn, M2, n0, (float*)d_out);
}

// Round 3
// 476.633 us; speedup vs baseline: 1.0496x; 1.0496x over previous
//
#include <hip/hip_runtime.h>
#include <hip/hip_bf16.h>
#include <cstdint>

// MCRNNVAE eval forward, algebraically collapsed:
//   h_{t+1} = tanh(x_t@R_c + r0_c + h_t@Q_c)
//   mu_t    = x_t@N_c + h_t@M2_c + n0_c
// R,Q,N,M2,r0,n0 precomputed from the raw weights (exact linear algebra).
// Round 7: kernB4 = proven kernB2 with two surgical changes:
//  (a) double-buffered hHi/hLo LDS -> ONE __syncthreads per step (was two);
//  (b) accumulator split into 4 independent chains (hi/lo separated), halving
//      the dependent MFMA chain 16 -> 8; summed once before tanh.
// Barriers stay plain __syncthreads() (round-2 showed hipcc's barrier
// scheduling beats manual lgkm-only asm barriers). kernU2/kernC3/pre* proven.

typedef __attribute__((ext_vector_type(8))) short short8;
typedef __attribute__((ext_vector_type(4))) float float4v;

__device__ __forceinline__ float bf2f(unsigned short u){
  union { unsigned int i; float f; } v; v.i = ((unsigned int)u) << 16; return v.f;
}
__device__ __forceinline__ unsigned short f2bf(float f){
  union { float f; unsigned int i; } v; v.f = f;
  unsigned int r = v.i + 0x7fffu + ((v.i >> 16) & 1u);
  return (unsigned short)(r >> 16);
}
__device__ __forceinline__ void st_bf2(unsigned short* p, float a, float b){
  unsigned int pa = f2bf(a), pb = f2bf(b);
  *(unsigned int*)p = pa | (pb << 16);
}
__device__ __forceinline__ float ftanh(float x){
  x = fminf(15.f, fmaxf(-15.f, x));
  float e = __expf(2.f * x);
  return (e - 1.f) * __builtin_amdgcn_rcpf(e + 1.f);
}

__device__ __forceinline__ float dotSB(const float* __restrict__ a,
                                       const float* __restrict__ b, int K, int ldb){
  float s = 0.f;
  #pragma unroll 4
  for (int k = 0; k < K; ++k) s = fmaf(a[k], b[(size_t)k * ldb], s);
  return s;
}

// ---- precompute stage 1: T1 = We1@Wqm, T2 = We2@Wqm, c0a = be@Wqm + bqm
__global__ void pre1(const float* __restrict__ encW, const float* __restrict__ encb,
                     const float* __restrict__ Wqm, const float* __restrict__ bqm,
                     float* __restrict__ T1, float* __restrict__ T2, float* __restrict__ c0a){
  int i = blockIdx.x * 256 + threadIdx.x;
  if (i < 24576){
    int c = i >> 13, rr = (i >> 6) & 127, l = i & 63;
    T1[i] = dotSB(encW + ((size_t)c*384 + rr)*128, Wqm + (size_t)c*8192 + l, 128, 64);
  } else if (i < 73728){
    int j = i - 24576; int c = j >> 14, rr = (j >> 6) & 255, l = j & 63;
    T2[j] = dotSB(encW + ((size_t)c*384 + 128 + rr)*128, Wqm + (size_t)c*8192 + l, 128, 64);
  } else if (i < 73920){
    int j = i - 73728; int c = j >> 6, l = j & 63;
    c0a[j] = dotSB(encb + c*128, Wqm + (size_t)c*8192 + l, 128, 64) + bqm[j];
  }
}

// ---- stage 2: A = T1@Wz, Bm = T2@Wz, c0 = c0a@Wz + bz
__global__ void pre2(const float* __restrict__ T1, const float* __restrict__ T2,
                     const float* __restrict__ c0a, const float* __restrict__ Wz,
                     const float* __restrict__ bz,
                     float* __restrict__ A, float* __restrict__ Bm, float* __restrict__ c0){
  int i = blockIdx.x * 256 + threadIdx.x;
  if (i < 49152){
    int c = i >> 14, rr = (i >> 7) & 127, n = i & 127;
    A[i] = dotSB(T1 + ((size_t)c*128 + rr)*64, Wz + n, 64, 128);
  } else if (i < 147456){
    int j = i - 49152; int c = j >> 15, rr = (j >> 7) & 255, n = j & 127;
    Bm[j] = dotSB(T2 + ((size_t)c*256 + rr)*64, Wz + n, 64, 128);
  } else if (i < 147840){
    int j = i - 147456; int c = j >> 7, n = j & 127;
    c0[j] = dotSB(c0a + c*64, Wz + n, 64, 128) + bz[n];
  }
}

// ---- stage 3: P = Wi1 + A@Wi2; Q = Whh + Bm@Wi2; r = c0@Wi2 + bih + bhh;
//               D1 = A@Wd1; E1 = Wd2 + Bm@Wd1; m0a = c0@Wd1 + bd
__global__ void pre3(const float* __restrict__ A, const float* __restrict__ Bm,
                     const float* __restrict__ c0, const float* __restrict__ Wih,
                     const float* __restrict__ Whh, const float* __restrict__ bih,
                     const float* __restrict__ bhh, const float* __restrict__ decW,
                     const float* __restrict__ decb,
                     float* __restrict__ P, float* __restrict__ Q, float* __restrict__ r,
                     float* __restrict__ D1, float* __restrict__ E1, float* __restrict__ m0a){
  int i = blockIdx.x * 256 + threadIdx.x;
  const float* Wi2 = Wih + 128*256;
  if (i < 98304){
    int c = i >> 15, rr = (i >> 8) & 127, n = i & 255;
    P[i] = Wih[rr*256 + n] + dotSB(A + ((size_t)c*128 + rr)*128, Wi2 + n, 128, 256);
  } else if (i < 294912){
    int j = i - 98304; int c = j >> 16, rr = (j >> 8) & 255, n = j & 255;
    Q[j] = Whh[rr*256 + n] + dotSB(Bm + ((size_t)c*256 + rr)*128, Wi2 + n, 128, 256);
  } else if (i < 295680){
    int j = i - 294912; int c = j >> 8, n = j & 255;
    r[j] = dotSB(c0 + c*128, Wi2 + n, 128, 256) + bih[n] + bhh[n];
  } else if (i < 344832){
    int j = i - 295680; int c = j >> 14, rr = (j >> 7) & 127, n = j & 127;
    D1[j] = dotSB(A + ((size_t)c*128 + rr)*128, decW + (size_t)c*49152 + n, 128, 128);
  } else if (i < 443136){
    int j = i - 344832; int c = j >> 15, rr = (j >> 7) & 255, n = j & 127;
    E1[j] = decW[(size_t)c*49152 + (size_t)(128 + rr)*128 + n]
          + dotSB(Bm + ((size_t)c*256 + rr)*128, decW + (size_t)c*49152 + n, 128, 128);
  } else if (i < 443520){
    int j = i - 443136; int c = j >> 7, n = j & 127;
    m0a[j] = dotSB(c0 + c*128, decW + (size_t)c*49152 + n, 128, 128) + decb[j];
  }
}

// ---- stage 4: R = Wx@P; r0 = bx@P + r; M1 = D1@Wpm; M2 = E1@Wpm; m0 = m0a@Wpm + bpm
__global__ void pre4(const float* __restrict__ Wx, const float* __restrict__ bx,
                     const float* __restrict__ P, const float* __restrict__ r,
                     const float* __restrict__ D1, const float* __restrict__ E1,
                     const float* __restrict__ m0a, const float* __restrict__ Wpm,
                     const float* __restrict__ bpm,
                     float* __restrict__ R, float* __restrict__ r0,
                     float* __restrict__ M1, float* __restrict__ M2, float* __restrict__ m0){
  int i = blockIdx.x * 256 + threadIdx.x;
  if (i < 98304){
    int c = i >> 15, rr = (i >> 8) & 127, n = i & 255;
    R[i] = dotSB(Wx + ((size_t)c*128 + rr)*128, P + (size_t)c*32768 + n, 128, 256);
  } else if (i < 99072){
    int j = i - 98304; int c = j >> 8, n = j & 255;
    r0[j] = dotSB(bx + c*128, P + (size_t)c*32768 + n, 128, 256) + r[j];
  } else if (i < 148224){
    int j = i - 99072; int c = j >> 14, rr = (j >> 7) & 127, n = j & 127;
    M1[j] = dotSB(D1 + ((size_t)c*128 + rr)*128, Wpm + (size_t)c*16384 + n, 128, 128);
  } else if (i < 246528){
    int j = i - 148224; int c = j >> 15, rr = (j >> 7) & 255, n = j & 127;
    M2[j] = dotSB(E1 + ((size_t)c*256 + rr)*128, Wpm + (size_t)c*16384 + n, 128, 128);
  } else if (i < 246912){
    int j = i - 246528; int c = j >> 7, n = j & 127;
    m0[j] = dotSB(m0a + c*128, Wpm + (size_t)c*16384 + n, 128, 128) + bpm[j];
  }
}

// ---- stage 5: Nn = Wx@M1; n0 = bx@M1 + m0
__global__ void pre5(const float* __restrict__ Wx, const float* __restrict__ bx,
                     const float* __restrict__ M1, const float* __restrict__ m0,
                     float* __restrict__ Nn, float* __restrict__ n0){
  int i = blockIdx.x * 256 + threadIdx.x;
  if (i < 49152){
    int c = i >> 14, rr = (i >> 7) & 127, n = i & 127;
    Nn[i] = dotSB(Wx + ((size_t)c*128 + rr)*128, M1 + (size_t)c*16384 + n, 128, 128);
  } else if (i < 49536){
    int j = i - 49152; int c = j >> 7, n = j & 127;
    n0[j] = dotSB(bx + c*128, M1 + (size_t)c*16384 + n, 128, 128) + m0[j];
  }
}

#define MFMA_BF16 __builtin_amdgcn_mfma_f32_16x16x32_bf16

// ---- kernU2: U = x@R + r0 (bf16 out) via MFMA. 1200 blocks x 512 thr (8 waves).
__global__ __launch_bounds__(512, 2)
void kernU2(const float* __restrict__ x, const float* __restrict__ Rg,
            const float* __restrict__ r0g, unsigned short* __restrict__ U){
  __shared__ unsigned short xs[128][136];
  const int m0 = blockIdx.x * 128;
  const int c  = m0 / 51200;                   // 400 blocks/channel, no straddle
  const int w  = threadIdx.x >> 6;
  const int l  = threadIdx.x & 63;
  const int q  = l >> 4, m = l & 15;
  const float* __restrict__ Rc = Rg + (size_t)c * 32768;   // [128][256]

  short8 rf[4][2];
  #pragma unroll
  for (int kt = 0; kt < 4; ++kt)
    #pragma unroll
    for (int nt = 0; nt < 2; ++nt){
      union { short8 v; unsigned short u[8]; } tmp;
      const int col = 32*w + 16*nt + m;
      #pragma unroll
      for (int j = 0; j < 8; ++j)
        tmp.u[j] = f2bf(Rc[(size_t)(32*kt + 8*q + j)*256 + col]);
      rf[kt][nt] = tmp.v;
    }
  const float r0v0 = r0g[c*256 + 32*w + m];
  const float r0v1 = r0g[c*256 + 32*w + 16 + m];

  {
    const int r  = threadIdx.x >> 2;
    const int c0 = (threadIdx.x & 3) * 32;
    const float* xr = x + (size_t)(m0 + r)*128 + c0;
    #pragma unroll
    for (int i = 0; i < 8; ++i){
      float4 v = *(const float4*)(xr + 4*i);
      st_bf2(&xs[r][c0 + 4*i],     v.x, v.y);
      st_bf2(&xs[r][c0 + 4*i + 2], v.z, v.w);
    }
  }
  __syncthreads();

  #pragma unroll 1
  for (int mt = 0; mt < 8; ++mt){
    float4v a0 = { r0v0, r0v0, r0v0, r0v0 };
    float4v a1 = { r0v1, r0v1, r0v1, r0v1 };
    #pragma unroll
    for (int kt = 0; kt < 4; ++kt){
      short8 af = *(const short8*)&xs[16*mt + m][32*kt + 8*q];
      a0 = MFMA_BF16(af, rf[kt][0], a0, 0,0,0);
      a1 = MFMA_BF16(af, rf[kt][1], a1, 0,0,0);
    }
    unsigned short* ub = U + (size_t)(m0 + 16*mt + 4*q)*256;
    ub[0*256 + 32*w + m]      = f2bf(a0.x);
    ub[1*256 + 32*w + m]      = f2bf(a0.y);
    ub[2*256 + 32*w + m]      = f2bf(a0.z);
    ub[3*256 + 32*w + m]      = f2bf(a0.w);
    ub[0*256 + 32*w + 16 + m] = f2bf(a1.x);
    ub[1*256 + 32*w + 16 + m] = f2bf(a1.y);
    ub[2*256 + 32*w + 16 + m] = f2bf(a1.z);
    ub[3*256 + 32*w + 16 + m] = f2bf(a1.w);
  }
}

// ---- kernB4: recurrence h_{t+1} = tanh(U_t + h_t@Q_c) via MFMA.
// 96 blocks = 3 channels x 32 (16 batch rows each), 512 threads = 8 waves.
// vs proven kernB2: (a) double-buffered hHi/hLo -> ONE __syncthreads/step;
// (b) 4 independent accumulator chains (hi/lo split), dependent chain 16->8.
__global__ __launch_bounds__(512, 2)
void kernB4(const unsigned short* __restrict__ U, const float* __restrict__ Qg,
            const float* __restrict__ h0, unsigned short* __restrict__ Hs){
  __shared__ unsigned short hHi[2][16][264];
  __shared__ unsigned short hLo[2][16][264];
  const int c  = blockIdx.x >> 5;
  const int b0 = (blockIdx.x & 31) << 4;
  const int w  = threadIdx.x >> 6;
  const int l  = threadIdx.x & 63;
  const int q  = l >> 4, m = l & 15;
  const float* __restrict__ Qc = Qg + (size_t)c * 65536;

  short8 qf[8][2];
  #pragma unroll
  for (int kt = 0; kt < 8; ++kt)
    #pragma unroll
    for (int nt = 0; nt < 2; ++nt){
      union { short8 v; unsigned short u[8]; } tmp;
      const int col = 32*w + 16*nt + m;
      #pragma unroll
      for (int j = 0; j < 8; ++j)
        tmp.u[j] = f2bf(Qc[(size_t)(32*kt + 8*q + j)*256 + col]);
      qf[kt][nt] = tmp.v;
    }

  unsigned short hiR[8];
  #pragma unroll
  for (int nt = 0; nt < 2; ++nt){
    const int col = 32*w + 16*nt + m;
    #pragma unroll
    for (int r = 0; r < 4; ++r){
      const int row = 4*q + r;
      float v = h0[((size_t)c*512 + b0 + row)*256 + col];
      unsigned short hi = f2bf(v);
      hiR[nt*4 + r] = hi;
      hHi[0][row][col] = hi;
      hLo[0][row][col] = f2bf(v - bf2f(hi));
    }
  }
  __syncthreads();

  unsigned short un[8];
  #pragma unroll
  for (int nt = 0; nt < 2; ++nt)
    #pragma unroll
    for (int r = 0; r < 4; ++r)
      un[nt*4 + r] = U[((size_t)(c*100 + 0)*512 + b0 + 4*q + r)*256 + 32*w + 16*nt + m];

  #pragma unroll 1
  for (int t = 0; t < 100; ++t){
    const int cur = t & 1, nxt = cur ^ 1;

    // store h_t (bf16) to Hs — fire-and-forget
    const size_t rowbase = (size_t)(c*100 + t)*512 + b0;
    #pragma unroll
    for (int nt = 0; nt < 2; ++nt)
      #pragma unroll
      for (int r = 0; r < 4; ++r)
        Hs[(rowbase + 4*q + r)*256 + 32*w + 16*nt + m] = hiR[nt*4 + r];

    // acc chains: hi-part seeded with U_t, lo-part zero (summed before tanh)
    float4v a0h = { bf2f(un[0]), bf2f(un[1]), bf2f(un[2]), bf2f(un[3]) };
    float4v a1h = { bf2f(un[4]), bf2f(un[5]), bf2f(un[6]), bf2f(un[7]) };
    float4v a0l = { 0.f, 0.f, 0.f, 0.f };
    float4v a1l = { 0.f, 0.f, 0.f, 0.f };

    // prefetch U_{t+1} (completes by this step's barrier drain)
    const int tn = (t < 99) ? t + 1 : 99;
    unsigned short unN[8];
    #pragma unroll
    for (int nt = 0; nt < 2; ++nt)
      #pragma unroll
      for (int r = 0; r < 4; ++r)
        unN[nt*4 + r] = U[((size_t)(c*100 + tn)*512 + b0 + 4*q + r)*256 + 32*w + 16*nt + m];

    #pragma unroll
    for (int kt = 0; kt < 8; ++kt){
      short8 ahi = *(const short8*)&hHi[cur][m][32*kt + 8*q];
      short8 alo = *(const short8*)&hLo[cur][m][32*kt + 8*q];
      a0h = MFMA_BF16(ahi, qf[kt][0], a0h, 0,0,0);
      a1h = MFMA_BF16(ahi, qf[kt][1], a1h, 0,0,0);
      a0l = MFMA_BF16(alo, qf[kt][0], a0l, 0,0,0);
      a1l = MFMA_BF16(alo, qf[kt][1], a1l, 0,0,0);
    }

    float hn[8];
    hn[0] = ftanh(a0h.x + a0l.x); hn[1] = ftanh(a0h.y + a0l.y);
    hn[2] = ftanh(a0h.z + a0l.z); hn[3] = ftanh(a0h.w + a0l.w);
    hn[4] = ftanh(a1h.x + a1l.x); hn[5] = ftanh(a1h.y + a1l.y);
    hn[6] = ftanh(a1h.z + a1l.z); hn[7] = ftanh(a1h.w + a1l.w);

    // write h_{t+1} into the NEXT buffers (no reader of nxt this step)
    #pragma unroll
    for (int nt = 0; nt < 2; ++nt){
      const int col = 32*w + 16*nt + m;
      #pragma unroll
      for (int r = 0; r < 4; ++r){
        const int row = 4*q + r;
        float v = hn[nt*4 + r];
        unsigned short hi = f2bf(v);
        hiR[nt*4 + r] = hi;
        hHi[nxt][row][col] = hi;
        hLo[nxt][row][col] = f2bf(v - bf2f(hi));
      }
    }
    #pragma unroll
    for (int i = 0; i < 8; ++i) un[i] = unN[i];

    __syncthreads();   // single barrier per step
  }
}

// ---- kernC3: out = x@Nn + Hs@M2 + n0 via MFMA. 1200 blocks x 512 thr. (proven)
__global__ __launch_bounds__(512, 2)
void kernC3(const float* __restrict__ x, const unsigned short* __restrict__ Hs,
            const float* __restrict__ Nn, const float* __restrict__ M2,
            const float* __restrict__ n0, float* __restrict__ out){
  __shared__ unsigned short xs[128][136];
  const int m0 = blockIdx.x * 128;
  const int c  = m0 / 51200;
  const int w  = threadIdx.x >> 6;
  const int l  = threadIdx.x & 63;
  const int q  = l >> 4, m = l & 15;
  const int col = 16*w + m;
  const float* __restrict__ Nc  = Nn + (size_t)c * 16384;   // [128][128]
  const float* __restrict__ M2c = M2 + (size_t)c * 32768;   // [256][128]

  short8 bw[12];
  #pragma unroll
  for (int kt = 0; kt < 4; ++kt){
    union { short8 v; unsigned short u[8]; } tmp;
    #pragma unroll
    for (int j = 0; j < 8; ++j)
      tmp.u[j] = f2bf(Nc[(size_t)(32*kt + 8*q + j)*128 + col]);
    bw[kt] = tmp.v;
  }
  #pragma unroll
  for (int kt = 0; kt < 8; ++kt){
    union { short8 v; unsigned short u[8]; } tmp;
    #pragma unroll
    for (int j = 0; j < 8; ++j)
      tmp.u[j] = f2bf(M2c[(size_t)(32*kt + 8*q + j)*128 + col]);
    bw[4 + kt] = tmp.v;
  }
  const float nz = n0[c*128 + col];

  {
    const int r  = threadIdx.x >> 2;
    const int c0 = (threadIdx.x & 3) * 32;
    const float* xr = x + (size_t)(m0 + r)*128 + c0;
    #pragma unroll
    for (int i = 0; i < 8; ++i){
      float4 v = *(const float4*)(xr + 4*i);
      st_bf2(&xs[r][c0 + 4*i],     v.x, v.y);
      st_bf2(&xs[r][c0 + 4*i + 2], v.z, v.w);
    }
  }
  __syncthreads();

  #pragma unroll 1
  for (int mt = 0; mt < 8; ++mt){
    float4v aa = { nz, nz, nz, nz }, ab = { 0.f, 0.f, 0.f, 0.f };
    #pragma unroll
    for (int kt = 0; kt < 4; ++kt){
      short8 af = *(const short8*)&xs[16*mt + m][32*kt + 8*q];
      if (kt & 1) ab = MFMA_BF16(af, bw[kt], ab, 0,0,0);
      else        aa = MFMA_BF16(af, bw[kt], aa, 0,0,0);
    }
    const size_t mrow = (size_t)(m0 + 16*mt) + m;
    #pragma unroll
    for (int kt = 0; kt < 8; ++kt){
      short8 af = *(const short8*)&Hs[mrow*256 + 32*kt + 8*q];
      if (kt & 1) ab = MFMA_BF16(af, bw[4+kt], ab, 0,0,0);
      else        aa = MFMA_BF16(af, bw[4+kt], aa, 0,0,0);
    }
    float* ob = out + (size_t)(m0 + 16*mt + 4*q)*128 + col;
    ob[0]   = aa.x + ab.x;
    ob[128] = aa.y + ab.y;
    ob[256] = aa.z + ab.z;
    ob[384] = aa.w + ab.w;
  }
}

extern "C" void kernel_launch(void* const* d_in, const int* in_sizes, int n_in,
                              void* d_out, int out_size, void* d_ws, size_t ws_size,
                              hipStream_t stream){
  const float* x    = (const float*)d_in[0];
  const float* Wx   = (const float*)d_in[1];
  const float* bx   = (const float*)d_in[2];
  const float* encW = (const float*)d_in[3];
  const float* encb = (const float*)d_in[4];
  const float* Wqm  = (const float*)d_in[5];
  const float* bqm  = (const float*)d_in[6];
  const float* Wz   = (const float*)d_in[7];
  const float* bz   = (const float*)d_in[8];
  const float* decW = (const float*)d_in[9];
  const float* decb = (const float*)d_in[10];
  const float* Wpm  = (const float*)d_in[11];
  const float* bpm  = (const float*)d_in[12];
  const float* Wih  = (const float*)d_in[13];
  const float* Whh  = (const float*)d_in[14];
  const float* bih  = (const float*)d_in[15];
  const float* bhh  = (const float*)d_in[16];
  const float* h0   = (const float*)d_in[17];

  float* ws = (float*)d_ws;
  size_t off = 0;
  auto alloc = [&](size_t n){ float* p = ws + off; off += n; return p; };
  float* T1  = alloc(24576);  float* T2  = alloc(49152);  float* c0a = alloc(192);
  float* A   = alloc(49152);  float* Bm  = alloc(98304);  float* c0  = alloc(384);
  float* P   = alloc(98304);  float* Q   = alloc(196608); float* r   = alloc(768);
  float* D1  = alloc(49152);  float* E1  = alloc(98304);  float* m0a = alloc(384);
  float* R   = alloc(98304);  float* r0  = alloc(768);
  float* M1  = alloc(49152);  float* M2  = alloc(98304);  float* m0  = alloc(384);
  float* Nn  = alloc(49152);  float* n0  = alloc(384);
  // Hs: 39,321,600 bf16 elements = 19,660,800 float slots (full size).
  unsigned short* Hs = (unsigned short*)(ws + off); off += 19660800;
  // U (bf16, 78.64 MB) lives in d_out (exact fit); consumed by kernB4 before
  // kernC3 overwrites d_out with the final result.
  unsigned short* U  = (unsigned short*)d_out;

  hipLaunchKernelGGL(pre1, dim3(289),  dim3(256), 0, stream, encW, encb, Wqm, bqm, T1, T2, c0a);
  hipLaunchKernelGGL(pre2, dim3(578),  dim3(256), 0, stream, T1, T2, c0a, Wz, bz, A, Bm, c0);
  hipLaunchKernelGGL(pre3, dim3(1733), dim3(256), 0, stream, A, Bm, c0, Wih, Whh, bih, bhh,
                     decW, decb, P, Q, r, D1, E1, m0a);
  hipLaunchKernelGGL(pre4, dim3(965),  dim3(256), 0, stream, Wx, bx, P, r, D1, E1, m0a,
                     Wpm, bpm, R, r0, M1, M2, m0);
  hipLaunchKernelGGL(pre5, dim3(194),  dim3(256), 0, stream, Wx, bx, M1, m0, Nn, n0);
  hipLaunchKernelGGL(kernU2, dim3(1200), dim3(512), 0, stream, x, R, r0, U);
  hipLaunchKernelGGL(kernB4, dim3(96),   dim3(512), 0, stream, U, Q, h0, Hs);
  hipLaunchKernelGGL(kernC3, dim3(1200), dim3(512), 0, stream, x, Hs, Nn, M2, n0, (float*)d_out);
}